// Round 14
// baseline (99.049 us; speedup 1.0000x reference)
//
#include <hip/hip_runtime.h>
#include <math.h>

constexpr int B = 256, STEP = 32, DF = 256, DZ = 64;
constexpr int NJC = 16;                  // j-chunks in k_z (16 j's each)
#define LOG_2PI 1.837877066409345f
#define LOG_C   16.36495572888985f       // log(256 * 50000)

__device__ __forceinline__ float warpReduceSum64(float v) {
    for (int o = 32; o > 0; o >>= 1) v += __shfl_down(v, o, 64);
    return v;
}

__device__ __forceinline__ float blockReduceSum256(float v, float* lds4) {
    int wid = threadIdx.x >> 6, lane = threadIdx.x & 63;
    v = warpReduceSum64(v);
    if (lane == 0) lds4[wid] = v;
    __syncthreads();
    float r = lds4[0] + lds4[1] + lds4[2] + lds4[3];
    __syncthreads();
    return r;
}

// K1: blocks 0..127: z elementwise -> emz rows [R][e(64)|me(64)], wc[R] (R = j*STEP+s).
//     blocks 128..143: f LDS-transpose -> eft4 (d-major), wcf_part.  (parts independent)
__global__ __launch_bounds__(256) void k1(
        const float* __restrict__ fm, const float* __restrict__ fl,
        const float* __restrict__ zm, const float* __restrict__ zl,
        float* __restrict__ emz, float* __restrict__ wc,
        float4* __restrict__ eft4, float* __restrict__ wcf_part) {
    int t = threadIdx.x;
    int wv = t >> 6, ln = t & 63;
    if (blockIdx.x < 128) {
        // 64 rows per block; iteration handles 4 consecutive rows (one per wave).
#pragma unroll 4
        for (int it = 0; it < 16; ++it) {
            int R = blockIdx.x * 64 + it * 4 + wv;
            float lv = zl[(size_t)R * DZ + ln];
            float m  = zm[(size_t)R * DZ + ln];
            float e = __expf(-lv);
            emz[(size_t)R * 128 + ln] = e;
            emz[(size_t)R * 128 + 64 + ln] = m * e;
            float r = warpReduceSum64(2.0f * lv);
            if (ln == 0) wc[R] = r + (float)DZ * LOG_2PI;
        }
    } else {
        __shared__ float te[64][65], tme[64][65];
        int fb = blockIdx.x - 128;            // 0..15
        int j0 = (fb & 3) * 64, d0 = (fb >> 2) * 64, dq = fb >> 2;
        float red[16];
#pragma unroll 4
        for (int it = 0; it < 16; ++it) {
            int jr = it * 4 + wv, jg = j0 + jr;
            size_t src = (size_t)jg * DF + d0 + ln;
            float lv = fl[src], m = fm[src];
            float e = __expf(-lv);
            te[ln][jr] = e;
            tme[ln][jr] = m * e;
            red[it] = 2.0f * lv;
        }
#pragma unroll
        for (int o = 32; o > 0; o >>= 1)
#pragma unroll
            for (int k = 0; k < 16; ++k) red[k] += __shfl_xor(red[k], o, 64);
        if (ln == 0) {
#pragma unroll
            for (int k = 0; k < 16; ++k)
                wcf_part[dq * B + j0 + k * 4 + wv] = red[k];
        }
        __syncthreads();
#pragma unroll
        for (int it = 0; it < 4; ++it) {
            int r = it * 4 + wv;
            int gr = (d0 >> 2) + r;
            float4 evv = make_float4(te[4 * r + 0][ln], te[4 * r + 1][ln],
                                     te[4 * r + 2][ln], te[4 * r + 3][ln]);
            float4 mvv = make_float4(tme[4 * r + 0][ln], tme[4 * r + 1][ln],
                                     tme[4 * r + 2][ln], tme[4 * r + 3][ln]);
            eft4[(size_t)gr * B + j0 + ln] = evv;
            eft4[(size_t)(64 + gr) * B + j0 + ln] = mvv;
        }
    }
}

// K2 = k_f: grid 128 (2 i's per block), 256 thr (j). Depth-3 pipelined panel reads;
// writes sum_fT[j][i] (transposed, float2) and hneg_f.
__global__ __launch_bounds__(256) void k_f(
        const float* __restrict__ fs, const float4* __restrict__ eft4,
        const float* __restrict__ wcf_part,
        float* __restrict__ sum_fT, float* __restrict__ hneg_f) {
    int ib = blockIdx.x * 2;
    int j = threadIdx.x;
    __shared__ float red2[2][4];
    const float4* f0 = reinterpret_cast<const float4*>(fs + (size_t)(ib + 0) * DF);
    const float4* f1 = reinterpret_cast<const float4*>(fs + (size_t)(ib + 1) * DF);
    const float4* ep = eft4 + j;
    const float4* mp = eft4 + (size_t)64 * B + j;
    float a0 = 0.0f, a1 = 0.0f;
    float4 eA = ep[0], mA = mp[0];
    float4 eB = ep[(size_t)B], mB = mp[(size_t)B];
    float4 eC = ep[(size_t)2 * B], mC = mp[(size_t)2 * B];
#pragma unroll
    for (int c = 0; c < 64; ++c) {
        float4 eN = make_float4(0.f, 0.f, 0.f, 0.f), mN = eN;
        if (c + 3 < 64) { eN = ep[(size_t)(c + 3) * B]; mN = mp[(size_t)(c + 3) * B]; }
        float4 s0 = f0[c], s1 = f1[c];
        float u0 = fmaf(s0.x, eA.x, -mA.x);
        float u1 = fmaf(s0.y, eA.y, -mA.y);
        float u2 = fmaf(s0.z, eA.z, -mA.z);
        float u3 = fmaf(s0.w, eA.w, -mA.w);
        a0 = fmaf(u0, u0, a0); a0 = fmaf(u1, u1, a0);
        a0 = fmaf(u2, u2, a0); a0 = fmaf(u3, u3, a0);
        float w0 = fmaf(s1.x, eA.x, -mA.x);
        float w1 = fmaf(s1.y, eA.y, -mA.y);
        float w2 = fmaf(s1.z, eA.z, -mA.z);
        float w3 = fmaf(s1.w, eA.w, -mA.w);
        a1 = fmaf(w0, w0, a1); a1 = fmaf(w1, w1, a1);
        a1 = fmaf(w2, w2, a1); a1 = fmaf(w3, w3, a1);
        eA = eB; mA = mB; eB = eC; mB = mC; eC = eN; mC = mN;
    }
    float wcf = wcf_part[j] + wcf_part[B + j] + wcf_part[2 * B + j]
              + wcf_part[3 * B + j] + (float)DF * LOG_2PI;
    float v0 = -0.5f * (a0 + wcf);
    float v1 = -0.5f * (a1 + wcf);
    *reinterpret_cast<float2*>(&sum_fT[(size_t)j * B + ib]) = make_float2(v0, v1);
    // 2-chain 256-thread LSE for hneg_f
    int wid = j >> 6, lane = j & 63;
    float m0 = v0, m1 = v1;
#pragma unroll
    for (int o = 32; o > 0; o >>= 1) {
        m0 = fmaxf(m0, __shfl_xor(m0, o, 64));
        m1 = fmaxf(m1, __shfl_xor(m1, o, 64));
    }
    if (lane == 0) { red2[0][wid] = m0; red2[1][wid] = m1; }
    __syncthreads();
    m0 = fmaxf(fmaxf(red2[0][0], red2[0][1]), fmaxf(red2[0][2], red2[0][3]));
    m1 = fmaxf(fmaxf(red2[1][0], red2[1][1]), fmaxf(red2[1][2], red2[1][3]));
    __syncthreads();
    float p0 = __expf(v0 - m0), p1 = __expf(v1 - m1);
#pragma unroll
    for (int o = 32; o > 0; o >>= 1) {
        p0 += __shfl_xor(p0, o, 64);
        p1 += __shfl_xor(p1, o, 64);
    }
    if (lane == 0) { red2[0][wid] = p0; red2[1][wid] = p1; }
    __syncthreads();
    if (j == 0) {
        float s0 = red2[0][0] + red2[0][1] + red2[0][2] + red2[0][3];
        float s1 = red2[1][0] + red2[1][1] + red2[1][2] + red2[1][3];
        hneg_f[ib + 0] = fmaxf(-(m0 + __logf(s0) - LOG_C), 0.0f);
        hneg_f[ib + 1] = fmaxf(-(m1 + __logf(s1) - LOG_C), 0.0f);
    }
}

// K3 = k_z: grid 512 (s = b&31 -> same-s blocks share an XCD; jc = b>>5), 256 thr (i).
// zs row in 64 VGPRs; e/me via block-uniform row loads; per-thread ONLINE LSE over 16 j.
// No LDS, no shuffles, no DS in the hot loop.
__global__ __launch_bounds__(256, 2) void k_z(
        const float* __restrict__ emz, const float* __restrict__ wc,
        const float* __restrict__ zs, const float* __restrict__ sum_fT,
        float* __restrict__ pmz, float* __restrict__ psz,
        float* __restrict__ pmfz, float* __restrict__ psfz) {
    int b = blockIdx.x;
    int s = b & 31, jc = b >> 5;
    int i = threadIdx.x;

    // own sample row -> registers (16 float4; per-lane lines fully consumed, L1-cached)
    const float4* zr = reinterpret_cast<const float4*>(zs + ((size_t)i * STEP + s) * DZ);
    float4 zsr[16];
#pragma unroll
    for (int c = 0; c < 16; ++c) zsr[c] = zr[c];

    float mz = -INFINITY, ez = 0.0f, mf = -INFINITY, ef = 0.0f;

    for (int jj = 0; jj < 16; ++jj) {
        int jrow = jc * 16 + jj;
        size_t R = (size_t)jrow * STEP + s;
        const float4* em = reinterpret_cast<const float4*>(emz + R * 128); // uniform
        float wcj = wc[R];                                 // uniform
        float sft = sum_fT[(size_t)jrow * B + i];          // coalesced
        float a0 = 0.0f, a1 = 0.0f, a2 = 0.0f, a3 = 0.0f;
#pragma unroll 8
        for (int c = 0; c < 16; ++c) {
            float4 e4 = em[c], me4 = em[16 + c];
            float4 sv = zsr[c];
            float t0 = fmaf(sv.x, e4.x, -me4.x);
            float t1 = fmaf(sv.y, e4.y, -me4.y);
            float t2 = fmaf(sv.z, e4.z, -me4.z);
            float t3 = fmaf(sv.w, e4.w, -me4.w);
            a0 = fmaf(t0, t0, a0);
            a1 = fmaf(t1, t1, a1);
            a2 = fmaf(t2, t2, a2);
            a3 = fmaf(t3, t3, a3);
        }
        float sz = -0.5f * ((a0 + a1) + (a2 + a3) + wcj);
        float szf = sz + sft;
        // online LSE updates (branchless)
        float nm = fmaxf(mz, sz);
        ez = ez * __expf(mz - nm) + __expf(sz - nm);
        mz = nm;
        float nf = fmaxf(mf, szf);
        ef = ef * __expf(mf - nf) + __expf(szf - nf);
        mf = nf;
    }
    size_t idx = ((size_t)s * NJC + jc) * B + i;
    pmz[idx] = mz;  psz[idx] = ez;
    pmfz[idx] = mf; psfz[idx] = ef;
}

// K4: grid 32 (s), 256 thr (i): combine 16 j-chunk LSE partials -> per-s sums.
__global__ __launch_bounds__(256) void k_comb(
        const float* __restrict__ pmz, const float* __restrict__ psz,
        const float* __restrict__ pmfz, const float* __restrict__ psfz,
        float* __restrict__ szsum, float* __restrict__ sfzsum) {
    __shared__ float lds4[4];
    int s = blockIdx.x, i = threadIdx.x;
    size_t base = (size_t)s * NJC * B + i;
    float pm[NJC], ps[NJC];
#pragma unroll
    for (int jc = 0; jc < NJC; ++jc) { pm[jc] = pmz[base + (size_t)jc * B]; ps[jc] = psz[base + (size_t)jc * B]; }
    float M = -INFINITY;
#pragma unroll
    for (int jc = 0; jc < NJC; ++jc) M = fmaxf(M, pm[jc]);
    float S = 0.0f;
#pragma unroll
    for (int jc = 0; jc < NJC; ++jc) S += ps[jc] * __expf(pm[jc] - M);
    float hz = fmaxf(-(M + __logf(S) - LOG_C), 0.0f);
#pragma unroll
    for (int jc = 0; jc < NJC; ++jc) { pm[jc] = pmfz[base + (size_t)jc * B]; ps[jc] = psfz[base + (size_t)jc * B]; }
    M = -INFINITY;
#pragma unroll
    for (int jc = 0; jc < NJC; ++jc) M = fmaxf(M, pm[jc]);
    S = 0.0f;
#pragma unroll
    for (int jc = 0; jc < NJC; ++jc) S += ps[jc] * __expf(pm[jc] - M);
    float hfz = fmaxf(-(M + __logf(S) - LOG_C), 0.0f);
    float rz = blockReduceSum256(hz, lds4);
    float rfz = blockReduceSum256(hfz, lds4);
    if (i == 0) { szsum[s] = rz; sfzsum[s] = rfz; }
}

// K5: 1 block finisher.
__global__ __launch_bounds__(256) void k_final(
        const float* __restrict__ hneg_f, const float* __restrict__ szsum,
        const float* __restrict__ sfzsum, float* __restrict__ out) {
    __shared__ float lds4[4];
    int t = threadIdx.x;
    float hf = hneg_f[t];
    float z = (t < STEP) ? szsum[t] : 0.0f;
    float fz = (t < STEP) ? sfzsum[t] : 0.0f;
    float Hf  = blockReduceSum256(hf, lds4) * (1.0f / B);
    float Hz  = blockReduceSum256(z, lds4) * (1.0f / (STEP * B));
    float Hfz = blockReduceSum256(fz, lds4) * (1.0f / (STEP * B));
    if (t == 0) out[0] = Hf + Hz - Hfz;
}

extern "C" void kernel_launch(void* const* d_in, const int* in_sizes, int n_in,
                              void* d_out, int out_size, void* d_ws, size_t ws_size,
                              hipStream_t stream) {
    const float* f_mean   = (const float*)d_in[0];
    const float* f_logvar = (const float*)d_in[1];
    const float* f_sample = (const float*)d_in[2];
    const float* z_mean   = (const float*)d_in[3];
    const float* z_logvar = (const float*)d_in[4];
    const float* z_sample = (const float*)d_in[5];
    float* out = (float*)d_out;

    float* w = (float*)d_ws;
    float* sum_fT   = w;  w += B * B;                 // 65536
    float* hneg_f   = w;  w += B;                     // 256
    float* emz      = w;  w += B * STEP * 128;        // 1M floats (4 MB)
    float* wc       = w;  w += B * STEP;              // 8192
    float4* eft4    = (float4*)w;  w += 128 * B * 4;  // 512 KB
    float* wcf_part = w;  w += 4 * B;                 // 1024
    float* pmz      = w;  w += STEP * NJC * B;        // 131072 each
    float* psz      = w;  w += STEP * NJC * B;
    float* pmfz     = w;  w += STEP * NJC * B;
    float* psfz     = w;  w += STEP * NJC * B;
    float* szsum    = w;  w += STEP;
    float* sfzsum   = w;  w += STEP;

    k1<<<dim3(144), dim3(256), 0, stream>>>(f_mean, f_logvar, z_mean, z_logvar,
                                            emz, wc, eft4, wcf_part);
    k_f<<<dim3(128), dim3(256), 0, stream>>>(f_sample, eft4, wcf_part, sum_fT, hneg_f);
    k_z<<<dim3(32 * NJC), dim3(256), 0, stream>>>(emz, wc, z_sample, sum_fT,
                                                  pmz, psz, pmfz, psfz);
    k_comb<<<dim3(STEP), dim3(256), 0, stream>>>(pmz, psz, pmfz, psfz, szsum, sfzsum);
    k_final<<<dim3(1), dim3(256), 0, stream>>>(hneg_f, szsum, sfzsum, out);
}

// Round 15
// 36.148 us; speedup vs baseline: 2.7401x; 2.7401x over previous
//
#include <hip/hip_runtime.h>
#include <math.h>

constexpr int B = 256, STEP = 32, DF = 256, DZ = 64;
constexpr int TI = 8;                    // i-tile per k_z block
#define LOG_2PI 1.837877066409345f
#define LOG_C   16.36495572888985f       // log(256 * 50000)

__device__ __forceinline__ float warpReduceSum64(float v) {
    for (int o = 32; o > 0; o >>= 1) v += __shfl_down(v, o, 64);
    return v;
}

// 256-thread block reduction; lds4 = float[4]; result valid in ALL threads.
__device__ __forceinline__ float blockReduceSum256(float v, float* lds4) {
    int wid = threadIdx.x >> 6, lane = threadIdx.x & 63;
    v = warpReduceSum64(v);
    if (lane == 0) lds4[wid] = v;
    __syncthreads();
    float r = lds4[0] + lds4[1] + lds4[2] + lds4[3];
    __syncthreads();
    return r;
}

// k_pre: tiled LDS transpose with transform -> VECTORIZED d-major layouts.
//  blocks 0..127:   z -> ezt4[s][r][j] (r<16 e-chunks, r>=16 me-chunks), wc.
//  blocks 128..143: f 64x64 tiles -> eft4 (r<64 e, r>=64 me), wcf_part[4][256].
__global__ __launch_bounds__(256) void k_pre(
        const float* __restrict__ fm, const float* __restrict__ fl,
        const float* __restrict__ zm, const float* __restrict__ zl,
        float4* __restrict__ ezt4, float* __restrict__ wc,
        float4* __restrict__ eft4, float* __restrict__ wcf_part) {
    int t = threadIdx.x;
    int wv = t >> 6, ln = t & 63;
    __shared__ float te[64][65], tme[64][65];   // padded: conflict-free both axes

    if (blockIdx.x < 128) {
        int s = blockIdx.x >> 2, j0 = (blockIdx.x & 3) * 64;
        float red[16];
#pragma unroll 4
        for (int it = 0; it < 16; ++it) {
            int jr = it * 4 + wv, jg = j0 + jr;
            size_t src = ((size_t)jg * STEP + s) * DZ + ln;   // 256B coalesced per wave
            float lv = zl[src], m = zm[src];
            float e = __expf(-lv);
            te[ln][jr] = e;
            tme[ln][jr] = m * e;
            red[it] = 2.0f * lv;
        }
#pragma unroll
        for (int o = 32; o > 0; o >>= 1)
#pragma unroll
            for (int k = 0; k < 16; ++k) red[k] += __shfl_xor(red[k], o, 64);
        if (ln == 0) {
#pragma unroll
            for (int k = 0; k < 16; ++k)
                wc[s * B + j0 + k * 4 + wv] = red[k] + (float)DZ * LOG_2PI;
        }
        __syncthreads();
        float4* ez = ezt4 + (size_t)s * 32 * B;
#pragma unroll
        for (int it = 0; it < 4; ++it) {
            int r = it * 4 + wv;   // chunk 0..15 (dims 4r..4r+3)
            float4 evv = make_float4(te[4 * r + 0][ln], te[4 * r + 1][ln],
                                     te[4 * r + 2][ln], te[4 * r + 3][ln]);
            float4 mvv = make_float4(tme[4 * r + 0][ln], tme[4 * r + 1][ln],
                                     tme[4 * r + 2][ln], tme[4 * r + 3][ln]);
            ez[(size_t)r * B + j0 + ln] = evv;          // 1KB coalesced per wave
            ez[(size_t)(16 + r) * B + j0 + ln] = mvv;
        }
    } else {
        int fb = blockIdx.x - 128;            // 0..15
        int j0 = (fb & 3) * 64, d0 = (fb >> 2) * 64, dq = fb >> 2;
        float red[16];
#pragma unroll 4
        for (int it = 0; it < 16; ++it) {
            int jr = it * 4 + wv, jg = j0 + jr;
            size_t src = (size_t)jg * DF + d0 + ln;   // 256B coalesced per wave
            float lv = fl[src], m = fm[src];
            float e = __expf(-lv);
            te[ln][jr] = e;
            tme[ln][jr] = m * e;
            red[it] = 2.0f * lv;
        }
#pragma unroll
        for (int o = 32; o > 0; o >>= 1)
#pragma unroll
            for (int k = 0; k < 16; ++k) red[k] += __shfl_xor(red[k], o, 64);
        if (ln == 0) {
#pragma unroll
            for (int k = 0; k < 16; ++k)
                wcf_part[dq * B + j0 + k * 4 + wv] = red[k];   // partial over 64 d's
        }
        __syncthreads();
#pragma unroll
        for (int it = 0; it < 4; ++it) {
            int r = it * 4 + wv;             // local chunk 0..15
            int gr = (d0 >> 2) + r;          // global chunk 0..63
            float4 evv = make_float4(te[4 * r + 0][ln], te[4 * r + 1][ln],
                                     te[4 * r + 2][ln], te[4 * r + 3][ln]);
            float4 mvv = make_float4(tme[4 * r + 0][ln], tme[4 * r + 1][ln],
                                     tme[4 * r + 2][ln], tme[4 * r + 3][ln]);
            eft4[(size_t)gr * B + j0 + ln] = evv;
            eft4[(size_t)(64 + gr) * B + j0 + ln] = mvv;
        }
    }
}

// k_f: grid = B/2 (2 i's per block), block = 512 (t = half*256 + j).
// Panel loads depth-3 pipelined; fs read as uniform (broadcast) loads.
__global__ __launch_bounds__(512, 2) void k_f(
        const float* __restrict__ fs, const float4* __restrict__ eft4,
        const float* __restrict__ wcf_part,
        float* __restrict__ sum_f, float* __restrict__ hneg_f) {
    int ib = blockIdx.x * 2;
    int t = threadIdx.x;
    int j = t & (B - 1), half = t >> 8;
    __shared__ float pacc[2][2][B];    // [half][i][j]
    __shared__ float red2[2][8];

    const float4* f0 = reinterpret_cast<const float4*>(fs + (size_t)(ib + 0) * DF) + half * 32;
    const float4* f1 = reinterpret_cast<const float4*>(fs + (size_t)(ib + 1) * DF) + half * 32;
    const float4* ep = eft4 + (size_t)(half * 32) * B + j;
    const float4* mp = eft4 + (size_t)(64 + half * 32) * B + j;
    float a0 = 0.0f, a1 = 0.0f;
    float4 eA = ep[0], mA = mp[0];
    float4 eB = ep[(size_t)B], mB = mp[(size_t)B];
    float4 eC = ep[(size_t)2 * B], mC = mp[(size_t)2 * B];
#pragma unroll
    for (int c = 0; c < 32; ++c) {
        float4 eN = make_float4(0.f, 0.f, 0.f, 0.f), mN = eN;
        if (c + 3 < 32) { eN = ep[(size_t)(c + 3) * B]; mN = mp[(size_t)(c + 3) * B]; }
        float4 s0 = f0[c];
        float4 s1 = f1[c];
        float u0 = fmaf(s0.x, eA.x, -mA.x);
        float u1 = fmaf(s0.y, eA.y, -mA.y);
        float u2 = fmaf(s0.z, eA.z, -mA.z);
        float u3 = fmaf(s0.w, eA.w, -mA.w);
        a0 = fmaf(u0, u0, a0); a0 = fmaf(u1, u1, a0);
        a0 = fmaf(u2, u2, a0); a0 = fmaf(u3, u3, a0);
        float w0 = fmaf(s1.x, eA.x, -mA.x);
        float w1 = fmaf(s1.y, eA.y, -mA.y);
        float w2 = fmaf(s1.z, eA.z, -mA.z);
        float w3 = fmaf(s1.w, eA.w, -mA.w);
        a1 = fmaf(w0, w0, a1); a1 = fmaf(w1, w1, a1);
        a1 = fmaf(w2, w2, a1); a1 = fmaf(w3, w3, a1);
        eA = eB; mA = mB; eB = eC; mB = mC; eC = eN; mC = mN;
    }
    pacc[half][0][j] = a0;
    pacc[half][1][j] = a1;
    __syncthreads();

    float v0 = -INFINITY, v1 = -INFINITY;
    if (t < B) {
        float wcf = wcf_part[j] + wcf_part[B + j] + wcf_part[2 * B + j]
                  + wcf_part[3 * B + j] + (float)DF * LOG_2PI;
        v0 = -0.5f * (pacc[0][0][j] + pacc[1][0][j] + wcf);
        v1 = -0.5f * (pacc[0][1][j] + pacc[1][1][j] + wcf);
        sum_f[(size_t)(ib + 0) * B + j] = v0;
        sum_f[(size_t)(ib + 1) * B + j] = v1;
    }
    // batched 2-chain 512-thread reduce (max then sum)
    int wid = t >> 6, lane = t & 63;
    float m0 = v0, m1 = v1;
#pragma unroll
    for (int o = 32; o > 0; o >>= 1) {
        m0 = fmaxf(m0, __shfl_xor(m0, o, 64));
        m1 = fmaxf(m1, __shfl_xor(m1, o, 64));
    }
    if (lane == 0) { red2[0][wid] = m0; red2[1][wid] = m1; }
    __syncthreads();
    m0 = -INFINITY; m1 = -INFINITY;
#pragma unroll
    for (int k = 0; k < 8; ++k) { m0 = fmaxf(m0, red2[0][k]); m1 = fmaxf(m1, red2[1][k]); }
    __syncthreads();
    float p0 = (t < B) ? __expf(v0 - m0) : 0.0f;
    float p1 = (t < B) ? __expf(v1 - m1) : 0.0f;
#pragma unroll
    for (int o = 32; o > 0; o >>= 1) {
        p0 += __shfl_xor(p0, o, 64);
        p1 += __shfl_xor(p1, o, 64);
    }
    if (lane == 0) { red2[0][wid] = p0; red2[1][wid] = p1; }
    __syncthreads();
    if (t == 0) {
        float s0 = 0.0f, s1 = 0.0f;
#pragma unroll
        for (int k = 0; k < 8; ++k) { s0 += red2[0][k]; s1 += red2[1][k]; }
        hneg_f[ib + 0] = fmaxf(-(m0 + __logf(s0) - LOG_C), 0.0f);
        hneg_f[ib + 1] = fmaxf(-(m1 + __logf(s1) - LOG_C), 0.0f);
    }
}

// k_z: 1024 blocks, XCD-swizzled so each XCD sees only 4 s-panels (L2-resident).
// b = x + 8*(it + 32*g): x = b&7 -> XCD group, it = (b>>3)&31, g = b>>8, s = x + 8*g.
__global__ __launch_bounds__(256, 4) void k_z(
        const float4* __restrict__ ezt4, const float* __restrict__ wc,
        const float* __restrict__ zs,
        const float* __restrict__ sum_f,
        float* __restrict__ hneg_z, float* __restrict__ hneg_fz) {
    int b = blockIdx.x;
    int x = b & 7, r = b >> 3;
    int it = r & 31, g = r >> 5;
    int s = x + 8 * g;
    int j = threadIdx.x;
    int i0 = it * TI;
    __shared__ float4 zs_sh[TI][16];           // 2 KB
    __shared__ float vls[2 * TI][260];         // 16.6 KB

    if (j < TI * 16) {   // stage TI zs rows (each row 256B contiguous)
        int ii = j >> 4, c = j & 15;
        zs_sh[ii][c] = *reinterpret_cast<const float4*>(
            &zs[((size_t)(i0 + ii) * STEP + s) * DZ + c * 4]);
    }
    __syncthreads();

    float wcj = wc[s * B + j];
    float sf[TI];
#pragma unroll
    for (int i = 0; i < TI; ++i) sf[i] = sum_f[(size_t)(i0 + i) * B + j];

    const float4* ev = ezt4 + (size_t)s * 32 * B + j;   // e chunks, lane-coalesced
    const float4* mv = ev + (size_t)16 * B;             // me chunks
    float acc[TI];
#pragma unroll
    for (int i = 0; i < TI; ++i) acc[i] = 0.0f;

    // depth-2 software pipeline over the 16 chunks
    float4 eA = ev[0], mA = mv[0];
    float4 eB = ev[(size_t)B], mB = mv[(size_t)B];
#pragma unroll
    for (int c = 0; c < 16; ++c) {
        float4 eN = make_float4(0.f, 0.f, 0.f, 0.f), mN = eN;
        if (c + 2 < 16) { eN = ev[(size_t)(c + 2) * B]; mN = mv[(size_t)(c + 2) * B]; }
#pragma unroll
        for (int i = 0; i < TI; ++i) {
            float4 sv = zs_sh[i][c];               // LDS broadcast (conflict-free)
            float t0 = fmaf(sv.x, eA.x, -mA.x);
            float t1 = fmaf(sv.y, eA.y, -mA.y);
            float t2 = fmaf(sv.z, eA.z, -mA.z);
            float t3 = fmaf(sv.w, eA.w, -mA.w);
            acc[i] = fmaf(t0, t0, acc[i]);
            acc[i] = fmaf(t1, t1, acc[i]);
            acc[i] = fmaf(t2, t2, acc[i]);
            acc[i] = fmaf(t3, t3, acc[i]);
        }
        eA = eB; mA = mB; eB = eN; mB = mN;
    }

    // ---- LSE via LDS transpose: thread j writes 16 chain values to column j ----
#pragma unroll
    for (int i = 0; i < TI; ++i) {
        float a = -0.5f * (acc[i] + wcj);
        vls[2 * i][j] = a;
        vls[2 * i + 1][j] = a + sf[i];
    }
    __syncthreads();

    // task k = j>>4 (16 threads, in-wave); thread e = j&15 reads 16 j-values (rotated).
    int k = j >> 4, e = j & 15;
    const float4* rowp = reinterpret_cast<const float4*>(&vls[k][0]);
    float4 q0 = rowp[e * 4 + ((e + 0) & 3)];
    float4 q1 = rowp[e * 4 + ((e + 1) & 3)];
    float4 q2 = rowp[e * 4 + ((e + 2) & 3)];
    float4 q3 = rowp[e * 4 + ((e + 3) & 3)];
    float m = fmaxf(fmaxf(fmaxf(q0.x, q0.y), fmaxf(q0.z, q0.w)),
                    fmaxf(fmaxf(q1.x, q1.y), fmaxf(q1.z, q1.w)));
    m = fmaxf(m, fmaxf(fmaxf(fmaxf(q2.x, q2.y), fmaxf(q2.z, q2.w)),
                       fmaxf(fmaxf(q3.x, q3.y), fmaxf(q3.z, q3.w))));
#pragma unroll
    for (int o = 1; o <= 8; o <<= 1) m = fmaxf(m, __shfl_xor(m, o, 64));
    float ssum = __expf(q0.x - m) + __expf(q0.y - m) + __expf(q0.z - m) + __expf(q0.w - m)
               + __expf(q1.x - m) + __expf(q1.y - m) + __expf(q1.z - m) + __expf(q1.w - m)
               + __expf(q2.x - m) + __expf(q2.y - m) + __expf(q2.z - m) + __expf(q2.w - m)
               + __expf(q3.x - m) + __expf(q3.y - m) + __expf(q3.z - m) + __expf(q3.w - m);
#pragma unroll
    for (int o = 1; o <= 8; o <<= 1) ssum += __shfl_xor(ssum, o, 64);
    if (e == 0) {
        float h = fmaxf(-(m + __logf(ssum) - LOG_C), 0.0f);
        int i = k >> 1;
        if (k & 1) hneg_fz[s * B + i0 + i] = h;
        else       hneg_z[s * B + i0 + i] = h;
    }
}

// k_final: 1 block, deterministic reduction -> scalar.
__global__ __launch_bounds__(256) void k_final(
        const float* __restrict__ hneg_f, const float* __restrict__ hneg_z,
        const float* __restrict__ hneg_fz, float* __restrict__ out) {
    __shared__ float lds4[4];
    int t = threadIdx.x;
    float sf = hneg_f[t];
    float szv = 0.0f, sfz = 0.0f;
#pragma unroll 8
    for (int k = 0; k < STEP; ++k) {       // fixed order per thread -> deterministic
        szv += hneg_z[k * B + t];
        sfz += hneg_fz[k * B + t];
    }
    float Hf  = blockReduceSum256(sf, lds4) * (1.0f / B);
    float Hz  = blockReduceSum256(szv, lds4) * (1.0f / (STEP * B));
    float Hfz = blockReduceSum256(sfz, lds4) * (1.0f / (STEP * B));
    if (t == 0) out[0] = Hf + Hz - Hfz;
}

extern "C" void kernel_launch(void* const* d_in, const int* in_sizes, int n_in,
                              void* d_out, int out_size, void* d_ws, size_t ws_size,
                              hipStream_t stream) {
    const float* f_mean   = (const float*)d_in[0];
    const float* f_logvar = (const float*)d_in[1];
    const float* f_sample = (const float*)d_in[2];
    const float* z_mean   = (const float*)d_in[3];
    const float* z_logvar = (const float*)d_in[4];
    const float* z_sample = (const float*)d_in[5];
    float* out = (float*)d_out;

    float* w = (float*)d_ws;
    float* sum_f    = w;  w += B * B;               // 65536
    float* hneg_f   = w;  w += B;                   // 256
    float* hneg_z   = w;  w += STEP * B;            // 8192
    float* hneg_fz  = w;  w += STEP * B;            // 8192
    float4* ezt4    = (float4*)w;  w += STEP * 32 * B * 4;   // 4 MB, [s][32][256] float4
    float* wc       = w;  w += STEP * B;            // 8192
    float4* eft4    = (float4*)w;  w += 128 * B * 4;         // 512 KB, [128][256] float4
    float* wcf_part = w;  w += 4 * B;               // 1024

    k_pre<<<dim3(144), dim3(256), 0, stream>>>(f_mean, f_logvar, z_mean, z_logvar,
                                               ezt4, wc, eft4, wcf_part);
    k_f<<<dim3(B / 2), dim3(512), 0, stream>>>(f_sample, eft4, wcf_part, sum_f, hneg_f);
    k_z<<<dim3((B / TI) * STEP), dim3(256), 0, stream>>>(ezt4, wc, z_sample,
                                                         sum_f, hneg_z, hneg_fz);
    k_final<<<dim3(1), dim3(256), 0, stream>>>(hneg_f, hneg_z, hneg_fz, out);
}